// Round 19
// baseline (228.614 us; speedup 1.0000x reference)
//
#include <hip/hip_runtime.h>
#include <hip/hip_bf16.h>
#include <math.h>

typedef unsigned short u16;
typedef short s16x8 __attribute__((ext_vector_type(8)));
typedef float f32x4 __attribute__((ext_vector_type(4)));
typedef unsigned u32x4 __attribute__((ext_vector_type(4)));

__device__ __host__ __forceinline__ int KP(int k) {
    return ((k & 12) << 1) | (((k >> 4) & 1) << 2) | (k & 3);
}

// gelu via Abramowitz-Stegun 7.1.26 erf (max abs err 1.5e-7)
__device__ __forceinline__ float geluf(float x) {
    float z = x * 0.70710678118654752f;
    float az = fabsf(z);
    float t = 1.0f / (1.0f + 0.3275911f * az);
    float p = t * (0.254829592f + t * (-0.284496736f + t * (1.421413741f +
              t * (-1.453152027f + t * 1.061405429f))));
    float erfa = 1.0f - p * __expf(-az * az);
    float erfz = copysignf(erfa, z);
    return 0.5f * x * (1.0f + erfz);
}
__device__ __forceinline__ u16 f2bf(float f) {
    unsigned u = __builtin_bit_cast(unsigned, f);
    return (u16)((u + 0x7fffu + ((u >> 16) & 1u)) >> 16);
}
__device__ __forceinline__ float bf2f(u16 h) {
    return __builtin_bit_cast(float, ((unsigned)h) << 16);
}
__device__ __forceinline__ void async_copy16(const u16* gsrc, u16* ldst) {
    __builtin_amdgcn_global_load_lds((const __attribute__((address_space(1))) void*)gsrc,
                                     (__attribute__((address_space(3))) void*)ldst, 16, 0, 0);
}
__device__ __forceinline__ float wave_reduce_sum(float v) {
    #pragma unroll
    for (int m = 32; m >= 1; m >>= 1) v += __shfl_xor(v, m, 64);
    return v;
}

// packed-bf16 |q-k| and q*k (proven R3/R8)
__device__ __forceinline__ s16x8 feat_abs(s16x8 k, s16x8 q) {
    u32x4 kk = __builtin_bit_cast(u32x4, k), qq = __builtin_bit_cast(u32x4, q);
    u32x4 o;
    #pragma unroll
    for (int p = 0; p < 4; ++p) {
        unsigned kp = kk[p], qp = qq[p];
        float klo = __builtin_bit_cast(float, kp << 16);
        float khi = __builtin_bit_cast(float, kp & 0xFFFF0000u);
        float qlo = __builtin_bit_cast(float, qp << 16);
        float qhi = __builtin_bit_cast(float, qp & 0xFFFF0000u);
        unsigned dlo = __builtin_bit_cast(unsigned, qlo - klo) & 0x7FFFFFFFu;
        unsigned dhi = __builtin_bit_cast(unsigned, qhi - khi) & 0x7FFFFFFFu;
        o[p] = (dhi & 0xFFFF0000u) | (dlo >> 16);
    }
    return __builtin_bit_cast(s16x8, o);
}
__device__ __forceinline__ s16x8 feat_mul(s16x8 k, s16x8 q) {
    u32x4 kk = __builtin_bit_cast(u32x4, k), qq = __builtin_bit_cast(u32x4, q);
    u32x4 o;
    #pragma unroll
    for (int p = 0; p < 4; ++p) {
        unsigned kp = kk[p], qp = qq[p];
        float klo = __builtin_bit_cast(float, kp << 16);
        float khi = __builtin_bit_cast(float, kp & 0xFFFF0000u);
        float qlo = __builtin_bit_cast(float, qp << 16);
        float qhi = __builtin_bit_cast(float, qp & 0xFFFF0000u);
        unsigned plo = __builtin_bit_cast(unsigned, qlo * klo);
        unsigned phi = __builtin_bit_cast(unsigned, qhi * khi);
        o[p] = (phi & 0xFFFF0000u) | (plo >> 16);
    }
    return __builtin_bit_cast(s16x8, o);
}

#define MFMA(a, b, c) __builtin_amdgcn_mfma_f32_16x16x32_bf16(a, b, c, 0, 0, 0)
#define WAITVM(n) asm volatile("s_waitcnt vmcnt(" #n ")" ::: "memory")
#define RAW_BARRIER() __builtin_amdgcn_s_barrier()
#define SCHED_FENCE() __builtin_amdgcn_sched_barrier(0)

// ---------- merged prep: Wk (3072 blks) | W1 (512) | W2' (128) | bias2 (1)
__global__ __launch_bounds__(256) void prep_all(
    const float* __restrict__ Wk, u16* __restrict__ wkt,
    const float* __restrict__ W1, u16* __restrict__ w1t,
    const float* __restrict__ W2, const float* __restrict__ g1,
    u16* __restrict__ w2t, const float* __restrict__ lnb,
    const float* __restrict__ b2, float* __restrict__ bias2)
{
    int blk = blockIdx.x, tid = threadIdx.x;
    if (blk < 3072) {
        int idx = blk * 256 + tid;              // 768*1024
        int k = idx >> 10, col = idx & 1023;
        int cb = col >> 7, ci = col & 127, kt = k >> 5, ki = k & 31;
        wkt[(size_t)(cb * 24 + kt) * 4096 + ci * 32 + KP(ki)] = f2bf(Wk[idx]);
    } else if (blk < 3584) {
        int idx = (blk - 3072) * 256 + tid;     // 512*256
        int k = idx >> 8, c = idx & 255;
        w1t[(size_t)(k >> 5) * 8192 + c * 32 + KP(k & 31)] = f2bf(W1[idx]);
    } else if (blk < 3712) {
        int idx = (blk - 3584) * 256 + tid;     // 256*128
        int k = idx >> 7, c = idx & 127;
        w2t[(size_t)(k >> 5) * 4096 + c * 32 + KP(k & 31)] = f2bf(g1[k] * W2[(size_t)k * 128 + c]);
    } else {
        int c = tid;
        if (c < 128) {
            float s = b2[c];
            for (int k = 0; k < 256; ++k) s += lnb[k] * W2[k * 128 + c];
            bias2[c] = s;
        }
    }
}

// ---------- nf = LN(ent + role_emb[roles]) -> blocked bf16 tiles [(row>>7)*24+kt][128][32 KP]
__global__ __launch_bounds__(256) void nf_ln_kernel(
    const float* __restrict__ ent, const int* __restrict__ roles,
    const float* __restrict__ role_emb, const float* __restrict__ g,
    const float* __restrict__ bta, u16* __restrict__ nfb)
{
    int wave = threadIdx.x >> 6, lane = threadIdx.x & 63;
    int row = blockIdx.x * 4 + wave;
    const float* er = ent + (size_t)row * 768;
    const float* rr = role_emb + roles[row] * 768;
    float x[12]; float s = 0.f, s2 = 0.f;
    #pragma unroll
    for (int i = 0; i < 12; ++i) {
        x[i] = er[i * 64 + lane] + rr[i * 64 + lane];
        s += x[i]; s2 += x[i] * x[i];
    }
    s = wave_reduce_sum(s); s2 = wave_reduce_sum(s2);
    float mu = s * (1.f / 768.f);
    float var = s2 * (1.f / 768.f) - mu * mu;
    float rs = rsqrtf(var + 1e-5f);
    size_t rb = (size_t)(row >> 7) * 24;
    int rin = row & 127;
    #pragma unroll
    for (int i = 0; i < 12; ++i) {
        int k = i * 64 + lane;
        float v = (x[i] - mu) * rs * g[k] + bta[k];
        nfb[(rb + (k >> 5)) * 4096 + rin * 32 + KP(k & 31)] = f2bf(v);
    }
}

// ---------- q = gelu(q_emb @ Wq + bq) -> bf16 [64][32 chunks][32 KP]
__global__ __launch_bounds__(256) void q_kernel(
    const float* __restrict__ q_emb, const float* __restrict__ Wq,
    const float* __restrict__ bq, u16* __restrict__ qout)
{
    __shared__ float sq[768];
    int b = blockIdx.y;
    int col = blockIdx.x * 256 + threadIdx.x;
    for (int i = threadIdx.x; i < 768; i += 256) sq[i] = q_emb[b * 768 + i];
    __syncthreads();
    float a[16];
    #pragma unroll
    for (int u = 0; u < 16; ++u) a[u] = 0.f;
    for (int k0 = 0; k0 < 768; k0 += 16) {
        #pragma unroll
        for (int u = 0; u < 16; ++u)
            a[u] = fmaf(sq[k0 + u], Wq[(size_t)(k0 + u) * 1024 + col], a[u]);
    }
    #pragma unroll
    for (int m = 8; m >= 1; m >>= 1)
        #pragma unroll
        for (int u = 0; u < m; ++u) a[u] += a[u + m];
    qout[b * 1024 + (col >> 5) * 32 + KP(col & 31)] = f2bf(geluf(a[0] + bq[col]));
}

// ---------- kgemm: nf[8192x768] @ Wk[768x1024] + gelu -> kbuf [8192 rows][32 chunks][32 KP]
__global__ __launch_bounds__(256) void kgemm(
    const u16* __restrict__ gA, const u16* __restrict__ gB,
    const float* __restrict__ bias, u16* __restrict__ kbuf)
{
    __shared__ __attribute__((aligned(16))) u16 As[2][4096];
    __shared__ __attribute__((aligned(16))) u16 Bs[2][4096];
    const int tid = threadIdx.x, lane = tid & 63, w = tid >> 6;
    const int lr = lane & 15, g = lane >> 4;
    const int wr = w >> 1, wc = w & 1;
    const int nb = blockIdx.x, mb = blockIdx.y;   // 8 x 64
    const int NT = 24;
    f32x4 acc[4][4];
    #pragma unroll
    for (int i = 0; i < 4; ++i)
        #pragma unroll
        for (int j = 0; j < 4; ++j) acc[i][j] = (f32x4){0.f, 0.f, 0.f, 0.f};

    auto stage = [&](int t, int bi) {
        #pragma unroll
        for (int i = 0; i < 2; ++i) {
            int c = w * 2 + i;   // 0..7
            async_copy16(gA + (size_t)(mb * 24 + t) * 4096 + c * 512 + lane * 8, As[bi] + c * 512);
            async_copy16(gB + (size_t)(nb * 24 + t) * 4096 + c * 512 + lane * 8, Bs[bi] + c * 512);
        }
    };
    stage(0, 0);
    __syncthreads();
    for (int t = 0; t < NT; ++t) {
        int cur = t & 1;
        if (t + 1 < NT) stage(t + 1, cur ^ 1);
        s16x8 bfr[4];
        #pragma unroll
        for (int j = 0; j < 4; ++j) bfr[j] = *(const s16x8*)&Bs[cur][(wc * 64 + j * 16 + lr) * 32 + g * 8];
        #pragma unroll
        for (int i = 0; i < 4; ++i) {
            s16x8 a = *(const s16x8*)&As[cur][(wr * 64 + i * 16 + lr) * 32 + g * 8];
            #pragma unroll
            for (int j = 0; j < 4; ++j) acc[i][j] = MFMA(a, bfr[j], acc[i][j]);
        }
        __syncthreads();
    }
    float bv[4];
    #pragma unroll
    for (int j = 0; j < 4; ++j) bv[j] = bias[nb * 128 + wc * 64 + j * 16 + lr];
    #pragma unroll
    for (int i = 0; i < 4; ++i)
        #pragma unroll
        for (int j = 0; j < 4; ++j) {
            int chunk = nb * 4 + wc * 2 + (j >> 1);
            int pos = ((lr & 12) << 1) | ((j & 1) << 2) | (lr & 3);
            #pragma unroll
            for (int r = 0; r < 4; ++r) {
                int row = mb * 128 + wr * 64 + i * 16 + 4 * g + r;
                kbuf[(size_t)row * 1024 + chunk * 32 + pos] = f2bf(geluf(acc[i][j][r] + bv[j]));
            }
        }
}

// ---------- h1h2: 512 blocks x 512 thr, ONE scheduling round (all blocks co-resident).
// Block = 128 rows' x 256 cols; 8 waves = 4 row-groups x 2 col-halves, wave = 32x128 (acc[2][8]).
// 16-step k-loop (Bs[3] counted-vmcnt, dt-rotation), cross-wave LN, 2-pass transpose + fused h2.
__global__ __launch_bounds__(512, 2) void h1(
    const u16* __restrict__ kbuf, const u16* __restrict__ qbuf,
    const u16* __restrict__ w1t, const float* __restrict__ b1v,
    const u16* __restrict__ w2t, const float* __restrict__ bias2,
    const float* __restrict__ g2v, const float* __restrict__ b2v,
    const float* __restrict__ W3, const float* __restrict__ b3,
    float* __restrict__ scores)
{
    __shared__ __attribute__((aligned(16))) u16 Bs[3][8192];   // 48KB; [0..1] reused as 32KB trans
    __shared__ float part[128][2][2];                           // 2KB
    const int tid = threadIdx.x, lane = tid & 63, wv = tid >> 6;   // 0..7
    const int lr = lane & 15, g = lane >> 4;
    const int wr = wv >> 1, wc = wv & 1;
    const int blk = blockIdx.x;              // rows' [blk*128, +128)
    const int b = blk >> 3;
    const int h = lr & 7;
    const int row0 = blk * 128 + wr * 32;    // wave's 32 rows'
    const int rot = blk & 3;                 // dt-rotation phase

    // per-lane A operands, PRE-ROTATED (chunk (dt+rot)&3 in slot dt)
    s16x8 qf[4], kvr[2][4];
    #pragma unroll
    for (int dt = 0; dt < 4; ++dt) {
        int ch = (dt + rot) & 3;
        qf[dt] = *(const s16x8*)&qbuf[(size_t)b * 1024 + (h * 4 + ch) * 32 + g * 8];
    }
    #pragma unroll
    for (int i = 0; i < 2; ++i) {
        int krow = (row0 + i * 16 + lr) >> 3;
        #pragma unroll
        for (int dt = 0; dt < 4; ++dt) {
            int ch = (dt + rot) & 3;
            kvr[i][dt] = *(const s16x8*)&kbuf[(size_t)krow * 1024 + (h * 4 + ch) * 32 + g * 8];
        }
    }

    // stage slab for loop position ks (512 thr -> 2 x 16B per thread)
    auto stage = [&](int ks, int bi) {
        int slab = (ks & 12) | ((ks + rot) & 3);
        #pragma unroll
        for (int c = 0; c < 2; ++c)
            async_copy16(w1t + (size_t)slab * 8192 + (c * 512 + tid) * 8,
                         Bs[bi] + (c * 512 + tid) * 8);
    };
    f32x4 acc[2][8];
    #pragma unroll
    for (int i = 0; i < 2; ++i)
        #pragma unroll
        for (int j = 0; j < 8; ++j) acc[i][j] = (f32x4){0.f, 0.f, 0.f, 0.f};

    stage(0, 0);
    stage(1, 1);
    #pragma unroll
    for (int ks = 0; ks < 16; ++ks) {     // fully unrolled: f, dt compile-time (rule #20)
        int cur = ks % 3;
        if (ks + 2 < 16) { stage(ks + 2, (ks + 2) % 3); WAITVM(4); }
        else if (ks + 1 < 16) WAITVM(2);
        else WAITVM(0);
        RAW_BARRIER();
        SCHED_FENCE();
        const int f = ks >> 2, dt = ks & 3;   // f: 0=q, 1=k, 2=|q-k|, 3=q*k
        s16x8 a0 = (f == 0) ? qf[dt] : (f == 1) ? kvr[0][dt]
                 : (f == 2) ? feat_abs(kvr[0][dt], qf[dt]) : feat_mul(kvr[0][dt], qf[dt]);
        s16x8 a1 = (f == 0) ? qf[dt] : (f == 1) ? kvr[1][dt]
                 : (f == 2) ? feat_abs(kvr[1][dt], qf[dt]) : feat_mul(kvr[1][dt], qf[dt]);
        #pragma unroll
        for (int j = 0; j < 8; ++j) {
            s16x8 bf = *(const s16x8*)&Bs[cur][(wc * 128 + j * 16 + lr) * 32 + g * 8];
            acc[0][j] = MFMA(a0, bf, acc[0][j]);
            acc[1][j] = MFMA(a1, bf, acc[1][j]);
        }
        SCHED_FENCE();
        RAW_BARRIER();
    }
    // epilogue: gelu(x + b1), cross-wave LN over 256 cols (128 rows)
    float b1c[8];
    #pragma unroll
    for (int j = 0; j < 8; ++j) b1c[j] = b1v[wc * 128 + j * 16 + lr];
    #pragma unroll
    for (int i = 0; i < 2; ++i) {
        float S[4] = {0.f, 0.f, 0.f, 0.f}, S2[4] = {0.f, 0.f, 0.f, 0.f};
        #pragma unroll
        for (int j = 0; j < 8; ++j) {
            f32x4 t = acc[i][j];
            #pragma unroll
            for (int r = 0; r < 4; ++r) {
                float v = geluf(t[r] + b1c[j]);
                t[r] = v; S[r] += v; S2[r] += v * v;
            }
            acc[i][j] = t;
        }
        #pragma unroll
        for (int r = 0; r < 4; ++r) {
            #pragma unroll
            for (int m = 1; m <= 8; m <<= 1) {
                S[r] += __shfl_xor(S[r], m, 64);
                S2[r] += __shfl_xor(S2[r], m, 64);
            }
            if (lr == 0) {
                int rowl = wr * 32 + i * 16 + 4 * g + r;
                part[rowl][wc][0] = S[r];
                part[rowl][wc][1] = S2[r];
            }
        }
    }
    __syncthreads();
    float c0[2][4], c1[2][4];
    #pragma unroll
    for (int i = 0; i < 2; ++i)
        #pragma unroll
        for (int r = 0; r < 4; ++r) {
            int rowl = wr * 32 + i * 16 + 4 * g + r;
            float S = part[rowl][0][0] + part[rowl][1][0];
            float S2 = part[rowl][0][1] + part[rowl][1][1];
            float mu = S * (1.f / 256.f);
            float var = S2 * (1.f / 256.f) - mu * mu;
            float rs = rsqrtf(var + 1e-5f);
            c1[i][r] = rs; c0[i][r] = -mu * rs;
        }
    // h2 per-wave constants (uniform; hoisted)
    float bc2[8], g2c[8], b2c[8], w3c[8];
    #pragma unroll
    for (int j = 0; j < 8; ++j) {
        int col = j * 16 + lr;
        bc2[j] = bias2[col]; g2c[j] = g2v[col]; b2c[j] = b2v[col]; w3c[j] = W3[col];
    }
    float b3v = b3[0];
    const u16* w2b = w2t + (size_t)lr * 32 + g * 8;   // + ks*4096 + j*512

    // 2-pass: pass p transposes rows [64p, 64p+64) into trans (32KB), then those rows' h2
    u16* trans = &Bs[0][0];
    #pragma unroll 1
    for (int p = 0; p < 2; ++p) {
        __syncthreads();
        if ((wr >> 1) == p) {   // row-groups 2p, 2p+1 write this pass
            #pragma unroll
            for (int i = 0; i < 2; ++i)
                #pragma unroll
                for (int j = 0; j < 8; ++j) {
                    int pos = wc * 128 + (j >> 1) * 32 + (((lr & 12) << 1) | ((j & 1) << 2) | (lr & 3));
                    #pragma unroll
                    for (int r = 0; r < 4; ++r) {
                        int rloc = (wr & 1) * 32 + i * 16 + 4 * g + r;   // 0..63
                        trans[rloc * 256 + pos] = f2bf(fmaf(acc[i][j][r], c1[i][r], c0[i][r]));
                    }
                }
        }
        __syncthreads();
        if ((wv >> 2) == p) {   // waves 4p..4p+3 run h2 on their 16-row slice
            s16x8 af2[8];
            #pragma unroll
            for (int ks = 0; ks < 8; ++ks)
                af2[ks] = *(const s16x8*)&trans[((wv & 3) * 16 + lr) * 256 + ks * 32 + g * 8];
            s16x8 bA2[8], bB2[8];
            #pragma unroll
            for (int j = 0; j < 8; ++j) bA2[j] = *(const s16x8*)(w2b + (size_t)j * 512);
            f32x4 acc2[8];
            #pragma unroll
            for (int j = 0; j < 8; ++j) acc2[j] = (f32x4){0.f, 0.f, 0.f, 0.f};
            #pragma unroll
            for (int kp = 0; kp < 4; ++kp) {
                const int ks0 = 2 * kp, ks1 = ks0 + 1;
                #pragma unroll
                for (int j = 0; j < 8; ++j)
                    bB2[j] = *(const s16x8*)(w2b + (size_t)ks1 * 4096 + j * 512);
                #pragma unroll
                for (int j = 0; j < 8; ++j) acc2[j] = MFMA(af2[ks0], bA2[j], acc2[j]);
                if (kp < 3) {
                    #pragma unroll
                    for (int j = 0; j < 8; ++j)
                        bA2[j] = *(const s16x8*)(w2b + (size_t)(ks0 + 2) * 4096 + j * 512);
                }
                #pragma unroll
                for (int j = 0; j < 8; ++j) acc2[j] = MFMA(af2[ks1], bB2[j], acc2[j]);
            }
            float T[4] = {0.f, 0.f, 0.f, 0.f}, T2[4] = {0.f, 0.f, 0.f, 0.f};
            #pragma unroll
            for (int j = 0; j < 8; ++j) {
                f32x4 t = acc2[j];
                #pragma unroll
                for (int r = 0; r < 4; ++r) {
                    float v = geluf(t[r] + bc2[j]);
                    t[r] = v; T[r] += v; T2[r] += v * v;
                }
                acc2[j] = t;
            }
            #pragma unroll
            for (int r = 0; r < 4; ++r) {
                #pragma unroll
                for (int m = 1; m <= 8; m <<= 1) {
                    T[r] += __shfl_xor(T[r], m, 64);
                    T2[r] += __shfl_xor(T2[r], m, 64);
                }
                float mu = T[r] * (1.f / 128.f);
                float var = T2[r] * (1.f / 128.f) - mu * mu;
                float rs = rsqrtf(var + 1e-5f);
                float dd = 0.f;
                #pragma unroll
                for (int j = 0; j < 8; ++j) {
                    float ln = (acc2[j][r] - mu) * rs * g2c[j] + b2c[j];
                    dd = fmaf(ln, w3c[j], dd);
                }
                #pragma unroll
                for (int m = 1; m <= 8; m <<= 1) dd += __shfl_xor(dd, m, 64);
                if (lr == 0)
                    scores[blk * 128 + p * 64 + (wv & 3) * 16 + 4 * g + r] = dd + b3v;
            }
        }
    }
}

// ---------- out[b] = sigmoid( sum_{n,h} score*gate*mask / 8 ), rows' = (b*128+n)*8+h
__global__ __launch_bounds__(256) void final_kernel(
    const float* __restrict__ scores, const float* __restrict__ idfs,
    const float* __restrict__ mask, const float* __restrict__ gate_w,
    const float* __restrict__ gate_b, float* __restrict__ outp)
{
    int b = blockIdx.x, tid = threadIdx.x;
    float gw = gate_w[0], gb = gate_b[0];
    float acc = 0.f;
    for (int i = tid; i < 1024; i += 256) {
        int n = i >> 3;
        float lg = log1pf(idfs[b * 128 + n]);
        float gate = 1.f / (1.f + expf(-(lg * gw + gb)));
        acc += scores[b * 1024 + i] * gate * mask[b * 128 + n];
    }
    acc = wave_reduce_sum(acc);
    __shared__ float wsum[4];
    if ((tid & 63) == 0) wsum[tid >> 6] = acc;
    __syncthreads();
    if (tid == 0) {
        float t = wsum[0] + wsum[1] + wsum[2] + wsum[3];
        outp[b] = 1.f / (1.f + expf(-t * 0.125f));
    }
}

extern "C" void kernel_launch(void* const* d_in, const int* in_sizes, int n_in,
                              void* d_out, int out_size, void* d_ws, size_t ws_size,
                              hipStream_t stream) {
    const float* q_emb    = (const float*)d_in[0];
    const float* ent      = (const float*)d_in[1];
    const int*   roles    = (const int*)d_in[2];
    const float* idfs     = (const float*)d_in[3];
    const float* mask     = (const float*)d_in[4];
    const float* role_emb = (const float*)d_in[5];
    const float* ln_f_g   = (const float*)d_in[6];
    const float* ln_f_b   = (const float*)d_in[7];
    const float* Wq       = (const float*)d_in[8];
    const float* bq       = (const float*)d_in[9];
    const float* Wk       = (const float*)d_in[10];
    const float* bk       = (const float*)d_in[11];
    const float* W1       = (const float*)d_in[12];
    const float* b1       = (const float*)d_in[13];
    const float* ln1_g    = (const float*)d_in[14];
    const float* ln1_b    = (const float*)d_in[15];
    const float* W2       = (const float*)d_in[16];
    const float* b2       = (const float*)d_in[17];
    const float* ln2_g    = (const float*)d_in[18];
    const float* ln2_b    = (const float*)d_in[19];
    const float* W3       = (const float*)d_in[20];
    const float* b3       = (const float*)d_in[21];
    const float* gate_w   = (const float*)d_in[22];
    const float* gate_b   = (const float*)d_in[23];
    float* outp = (float*)d_out;

    // workspace layout (bytes), disjoint; peak ~32 MB
    char* ws = (char*)d_ws;
    u16*   nfb    = (u16*)(ws);                          // 12,582,912
    u16*   kbuf   = (u16*)(ws + (size_t)12582912);       // 16,777,216
    u16*   WkT    = (u16*)(ws + (size_t)29360128);       //  1,572,864
    u16*   W1T    = (u16*)(ws + (size_t)30932992);       //    262,144
    u16*   W2T    = (u16*)(ws + (size_t)31195136);       //     65,536
    u16*   qbuf   = (u16*)(ws + (size_t)31260672);       //    131,072
    float* bias2  = (float*)(ws + (size_t)31391744);     //        512
    float* scores = (float*)(ws + (size_t)31392256);     //    262,144

    prep_all<<<3713, 256, 0, stream>>>(Wk, WkT, W1, W1T, W2, ln1_g, W2T, ln1_b, b2, bias2);
    nf_ln_kernel<<<2048, 256, 0, stream>>>(ent, roles, role_emb, ln_f_g, ln_f_b, nfb);
    q_kernel<<<dim3(4, 64), 256, 0, stream>>>(q_emb, Wq, bq, qbuf);
    kgemm<<<dim3(8, 64), 256, 0, stream>>>(nfb, WkT, bk, kbuf);
    h1<<<512, 512, 0, stream>>>(kbuf, qbuf, W1T, b1, W2T, bias2,
                                ln2_g, ln2_b, W3, b3, scores);
    final_kernel<<<64, 256, 0, stream>>>(scores, idfs, mask, gate_w, gate_b, outp);
}

// Round 20
// 135.887 us; speedup vs baseline: 1.6824x; 1.6824x over previous
//
#include <hip/hip_runtime.h>
#include <hip/hip_bf16.h>
#include <math.h>

typedef unsigned short u16;
typedef short s16x8 __attribute__((ext_vector_type(8)));
typedef float f32x4 __attribute__((ext_vector_type(4)));
typedef unsigned u32x4 __attribute__((ext_vector_type(4)));

// k-interleave within a 32-wide k-tile: lane group g reads contiguous 16B =
// k [4g..4g+3, 16+4g..16+4g+3]
__device__ __host__ __forceinline__ int KP(int k) {
    return ((k & 12) << 1) | (((k >> 4) & 1) << 2) | (k & 3);
}

// gelu via Abramowitz-Stegun 7.1.26 erf (max abs err 1.5e-7) — ~17 VALU ops vs ~120 for libm erff
__device__ __forceinline__ float geluf(float x) {
    float z = x * 0.70710678118654752f;
    float az = fabsf(z);
    float t = 1.0f / (1.0f + 0.3275911f * az);
    float p = t * (0.254829592f + t * (-0.284496736f + t * (1.421413741f +
              t * (-1.453152027f + t * 1.061405429f))));
    float erfa = 1.0f - p * __expf(-az * az);
    float erfz = copysignf(erfa, z);
    return 0.5f * x * (1.0f + erfz);
}
__device__ __forceinline__ u16 f2bf(float f) {
    unsigned u = __builtin_bit_cast(unsigned, f);
    return (u16)((u + 0x7fffu + ((u >> 16) & 1u)) >> 16);
}
__device__ __forceinline__ float bf2f(u16 h) {
    return __builtin_bit_cast(float, ((unsigned)h) << 16);
}
__device__ __forceinline__ void async_copy16(const u16* gsrc, u16* ldst) {
    __builtin_amdgcn_global_load_lds((const __attribute__((address_space(1))) void*)gsrc,
                                     (__attribute__((address_space(3))) void*)ldst, 16, 0, 0);
}
__device__ __forceinline__ float wave_reduce_sum(float v) {
    #pragma unroll
    for (int m = 32; m >= 1; m >>= 1) v += __shfl_xor(v, m, 64);
    return v;
}

// packed-bf16 |q-k| and q*k (proven R3/R8)
__device__ __forceinline__ s16x8 feat_abs(s16x8 k, s16x8 q) {
    u32x4 kk = __builtin_bit_cast(u32x4, k), qq = __builtin_bit_cast(u32x4, q);
    u32x4 o;
    #pragma unroll
    for (int p = 0; p < 4; ++p) {
        unsigned kp = kk[p], qp = qq[p];
        float klo = __builtin_bit_cast(float, kp << 16);
        float khi = __builtin_bit_cast(float, kp & 0xFFFF0000u);
        float qlo = __builtin_bit_cast(float, qp << 16);
        float qhi = __builtin_bit_cast(float, qp & 0xFFFF0000u);
        unsigned dlo = __builtin_bit_cast(unsigned, qlo - klo) & 0x7FFFFFFFu;
        unsigned dhi = __builtin_bit_cast(unsigned, qhi - khi) & 0x7FFFFFFFu;
        o[p] = (dhi & 0xFFFF0000u) | (dlo >> 16);
    }
    return __builtin_bit_cast(s16x8, o);
}
__device__ __forceinline__ s16x8 feat_mul(s16x8 k, s16x8 q) {
    u32x4 kk = __builtin_bit_cast(u32x4, k), qq = __builtin_bit_cast(u32x4, q);
    u32x4 o;
    #pragma unroll
    for (int p = 0; p < 4; ++p) {
        unsigned kp = kk[p], qp = qq[p];
        float klo = __builtin_bit_cast(float, kp << 16);
        float khi = __builtin_bit_cast(float, kp & 0xFFFF0000u);
        float qlo = __builtin_bit_cast(float, qp << 16);
        float qhi = __builtin_bit_cast(float, qp & 0xFFFF0000u);
        unsigned plo = __builtin_bit_cast(unsigned, qlo * klo);
        unsigned phi = __builtin_bit_cast(unsigned, qhi * khi);
        o[p] = (phi & 0xFFFF0000u) | (plo >> 16);
    }
    return __builtin_bit_cast(s16x8, o);
}

#define MFMA(a, b, c) __builtin_amdgcn_mfma_f32_16x16x32_bf16(a, b, c, 0, 0, 0)
#define WAITVM(n) asm volatile("s_waitcnt vmcnt(" #n ")" ::: "memory")
#define RAW_BARRIER() __builtin_amdgcn_s_barrier()
#define SCHED_FENCE() __builtin_amdgcn_sched_barrier(0)

// ---------- merged prep: Wk (3072 blks) | W1 (512) | W2' (128) | bias2 (1)
__global__ __launch_bounds__(256) void prep_all(
    const float* __restrict__ Wk, u16* __restrict__ wkt,
    const float* __restrict__ W1, u16* __restrict__ w1t,
    const float* __restrict__ W2, const float* __restrict__ g1,
    u16* __restrict__ w2t, const float* __restrict__ lnb,
    const float* __restrict__ b2, float* __restrict__ bias2)
{
    int blk = blockIdx.x, tid = threadIdx.x;
    if (blk < 3072) {
        int idx = blk * 256 + tid;              // 768*1024, K=768 N=1024 CB=128
        int k = idx >> 10, col = idx & 1023;
        int cb = col >> 7, ci = col & 127, kt = k >> 5, ki = k & 31;
        wkt[(size_t)(cb * 24 + kt) * 4096 + ci * 32 + KP(ki)] = f2bf(Wk[idx]);
    } else if (blk < 3584) {
        int idx = (blk - 3072) * 256 + tid;     // 512*256
        int k = idx >> 8, c = idx & 255;
        w1t[(size_t)(k >> 5) * 8192 + c * 32 + KP(k & 31)] = f2bf(W1[idx]);
    } else if (blk < 3712) {
        int idx = (blk - 3584) * 256 + tid;     // 256*128
        int k = idx >> 7, c = idx & 127;
        w2t[(size_t)(k >> 5) * 4096 + c * 32 + KP(k & 31)] = f2bf(g1[k] * W2[(size_t)k * 128 + c]);
    } else {
        int c = tid;
        if (c < 128) {
            float s = b2[c];
            for (int k = 0; k < 256; ++k) s += lnb[k] * W2[k * 128 + c];
            bias2[c] = s;
        }
    }
}

// ---------- nf = LN(ent + role_emb[roles]) -> blocked bf16 tiles [(row>>7)*24+kt][128][32 KP]
__global__ __launch_bounds__(256) void nf_ln_kernel(
    const float* __restrict__ ent, const int* __restrict__ roles,
    const float* __restrict__ role_emb, const float* __restrict__ g,
    const float* __restrict__ bta, u16* __restrict__ nfb)
{
    int wave = threadIdx.x >> 6, lane = threadIdx.x & 63;
    int row = blockIdx.x * 4 + wave;
    const float* er = ent + (size_t)row * 768;
    const float* rr = role_emb + roles[row] * 768;
    float x[12]; float s = 0.f, s2 = 0.f;
    #pragma unroll
    for (int i = 0; i < 12; ++i) {
        x[i] = er[i * 64 + lane] + rr[i * 64 + lane];
        s += x[i]; s2 += x[i] * x[i];
    }
    s = wave_reduce_sum(s); s2 = wave_reduce_sum(s2);
    float mu = s * (1.f / 768.f);
    float var = s2 * (1.f / 768.f) - mu * mu;
    float rs = rsqrtf(var + 1e-5f);
    size_t rb = (size_t)(row >> 7) * 24;
    int rin = row & 127;
    #pragma unroll
    for (int i = 0; i < 12; ++i) {
        int k = i * 64 + lane;
        float v = (x[i] - mu) * rs * g[k] + bta[k];
        nfb[(rb + (k >> 5)) * 4096 + rin * 32 + KP(k & 31)] = f2bf(v);
    }
}

// ---------- q = gelu(q_emb @ Wq + bq) -> bf16 [64][32 chunks][32 KP]
__global__ __launch_bounds__(256) void q_kernel(
    const float* __restrict__ q_emb, const float* __restrict__ Wq,
    const float* __restrict__ bq, u16* __restrict__ qout)
{
    __shared__ float sq[768];
    int b = blockIdx.y;
    int col = blockIdx.x * 256 + threadIdx.x;
    for (int i = threadIdx.x; i < 768; i += 256) sq[i] = q_emb[b * 768 + i];
    __syncthreads();
    float a[16];
    #pragma unroll
    for (int u = 0; u < 16; ++u) a[u] = 0.f;
    for (int k0 = 0; k0 < 768; k0 += 16) {
        #pragma unroll
        for (int u = 0; u < 16; ++u)
            a[u] = fmaf(sq[k0 + u], Wq[(size_t)(k0 + u) * 1024 + col], a[u]);
    }
    #pragma unroll
    for (int m = 8; m >= 1; m >>= 1)
        #pragma unroll
        for (int u = 0; u < m; ++u) a[u] += a[u + m];
    qout[b * 1024 + (col >> 5) * 32 + KP(col & 31)] = f2bf(geluf(a[0] + bq[col]));
}

// ---------- kgemm: nf[8192x768] @ Wk[768x1024] + gelu -> kbuf [8192 rows][32 chunks][32 KP]
__global__ __launch_bounds__(256) void kgemm(
    const u16* __restrict__ gA, const u16* __restrict__ gB,
    const float* __restrict__ bias, u16* __restrict__ kbuf)
{
    __shared__ __attribute__((aligned(16))) u16 As[2][4096];
    __shared__ __attribute__((aligned(16))) u16 Bs[2][4096];
    const int tid = threadIdx.x, lane = tid & 63, w = tid >> 6;
    const int lr = lane & 15, g = lane >> 4;
    const int wr = w >> 1, wc = w & 1;
    const int nb = blockIdx.x, mb = blockIdx.y;   // 8 x 64
    const int NT = 24;
    f32x4 acc[4][4];
    #pragma unroll
    for (int i = 0; i < 4; ++i)
        #pragma unroll
        for (int j = 0; j < 4; ++j) acc[i][j] = (f32x4){0.f, 0.f, 0.f, 0.f};

    auto stage = [&](int t, int bi) {
        #pragma unroll
        for (int i = 0; i < 2; ++i) {
            int c = w * 2 + i;   // 0..7
            async_copy16(gA + (size_t)(mb * 24 + t) * 4096 + c * 512 + lane * 8, As[bi] + c * 512);
            async_copy16(gB + (size_t)(nb * 24 + t) * 4096 + c * 512 + lane * 8, Bs[bi] + c * 512);
        }
    };
    stage(0, 0);
    __syncthreads();
    for (int t = 0; t < NT; ++t) {
        int cur = t & 1;
        if (t + 1 < NT) stage(t + 1, cur ^ 1);
        s16x8 bfr[4];
        #pragma unroll
        for (int j = 0; j < 4; ++j) bfr[j] = *(const s16x8*)&Bs[cur][(wc * 64 + j * 16 + lr) * 32 + g * 8];
        #pragma unroll
        for (int i = 0; i < 4; ++i) {
            s16x8 a = *(const s16x8*)&As[cur][(wr * 64 + i * 16 + lr) * 32 + g * 8];
            #pragma unroll
            for (int j = 0; j < 4; ++j) acc[i][j] = MFMA(a, bfr[j], acc[i][j]);
        }
        __syncthreads();
    }
    float bv[4];
    #pragma unroll
    for (int j = 0; j < 4; ++j) bv[j] = bias[nb * 128 + wc * 64 + j * 16 + lr];
    #pragma unroll
    for (int i = 0; i < 4; ++i)
        #pragma unroll
        for (int j = 0; j < 4; ++j) {
            int chunk = nb * 4 + wc * 2 + (j >> 1);
            int pos = ((lr & 12) << 1) | ((j & 1) << 2) | (lr & 3);
            #pragma unroll
            for (int r = 0; r < 4; ++r) {
                int row = mb * 128 + wr * 64 + i * 16 + 4 * g + r;
                kbuf[(size_t)row * 1024 + chunk * 32 + pos] = f2bf(geluf(acc[i][j][r] + bv[j]));
            }
        }
}

// ---------- h1h2: interaction[65536x512] @ W1 (+b1, gelu, LN) then @ W2' (+bias2, gelu, LN, W3)
// rows' = (b*128+n)*8+h. 1024 blocks x 256 thr. dt-ROTATION (rot = blk&3).
__global__ __launch_bounds__(256, 2) void h1(
    const u16* __restrict__ kbuf, const u16* __restrict__ qbuf,
    const u16* __restrict__ w1t, const float* __restrict__ b1v,
    const u16* __restrict__ w2t, const float* __restrict__ bias2,
    const float* __restrict__ g2v, const float* __restrict__ b2v,
    const float* __restrict__ W3, const float* __restrict__ b3,
    float* __restrict__ scores)
{
    __shared__ __attribute__((aligned(16))) u16 Bs[3][8192];   // 48KB, reused for transpose
    __shared__ float part[64][2][2];                            // 1KB
    const int tid = threadIdx.x, lane = tid & 63, wv = tid >> 6;
    const int lr = lane & 15, g = lane >> 4;
    const int wr = wv >> 1, wc = wv & 1;
    const int blk = blockIdx.x;             // rows' [blk*64, +64)
    const int b = blk >> 4;
    const int h = lr & 7;
    const int row0 = blk * 64 + wr * 32;    // wave's 32 rows'
    const int rot = blk & 3;                // dt-rotation phase

    // per-lane A operands, PRE-ROTATED: qf[dt]/kvr[i][dt] hold d-chunk (dt+rot)&3
    s16x8 qf[4], kvr[2][4];
    #pragma unroll
    for (int dt = 0; dt < 4; ++dt) {
        int ch = (dt + rot) & 3;
        qf[dt] = *(const s16x8*)&qbuf[(size_t)b * 1024 + (h * 4 + ch) * 32 + g * 8];
    }
    #pragma unroll
    for (int i = 0; i < 2; ++i) {
        int krow = (row0 + i * 16 + lr) >> 3;
        #pragma unroll
        for (int dt = 0; dt < 4; ++dt) {
            int ch = (dt + rot) & 3;
            kvr[i][dt] = *(const s16x8*)&kbuf[(size_t)krow * 1024 + (h * 4 + ch) * 32 + g * 8];
        }
    }

    // stage slab for loop position ks: actual slab = f*4 + ((dt+rot)&3)
    auto stage = [&](int ks, int bi) {
        int slab = (ks & 12) | ((ks + rot) & 3);
        #pragma unroll
        for (int c = 0; c < 4; ++c)
            async_copy16(w1t + (size_t)slab * 8192 + (c * 256 + tid) * 8, Bs[bi] + (c * 256 + tid) * 8);
    };
    f32x4 acc[2][8];
    #pragma unroll
    for (int i = 0; i < 2; ++i)
        #pragma unroll
        for (int j = 0; j < 8; ++j) acc[i][j] = (f32x4){0.f, 0.f, 0.f, 0.f};

    stage(0, 0);
    stage(1, 1);
    #pragma unroll
    for (int ks = 0; ks < 16; ++ks) {     // fully unrolled: f, dt compile-time (rule #20)
        int cur = ks % 3;
        if (ks + 2 < 16) { stage(ks + 2, (ks + 2) % 3); WAITVM(8); }
        else if (ks + 1 < 16) WAITVM(4);
        else WAITVM(0);
        RAW_BARRIER();
        SCHED_FENCE();
        const int f = ks >> 2, dt = ks & 3;   // f: 0=q, 1=k, 2=|q-k|, 3=q*k
        s16x8 a0 = (f == 0) ? qf[dt] : (f == 1) ? kvr[0][dt]
                 : (f == 2) ? feat_abs(kvr[0][dt], qf[dt]) : feat_mul(kvr[0][dt], qf[dt]);
        s16x8 a1 = (f == 0) ? qf[dt] : (f == 1) ? kvr[1][dt]
                 : (f == 2) ? feat_abs(kvr[1][dt], qf[dt]) : feat_mul(kvr[1][dt], qf[dt]);
        #pragma unroll
        for (int j = 0; j < 8; ++j) {
            s16x8 bf = *(const s16x8*)&Bs[cur][(wc * 128 + j * 16 + lr) * 32 + g * 8];
            acc[0][j] = MFMA(a0, bf, acc[0][j]);
            acc[1][j] = MFMA(a1, bf, acc[1][j]);
        }
        SCHED_FENCE();
        RAW_BARRIER();
    }
    // epilogue: gelu(x + b1), cross-wave LN over 256 cols
    float b1c[8];
    #pragma unroll
    for (int j = 0; j < 8; ++j) b1c[j] = b1v[wc * 128 + j * 16 + lr];
    #pragma unroll
    for (int i = 0; i < 2; ++i) {
        float S[4] = {0.f, 0.f, 0.f, 0.f}, S2[4] = {0.f, 0.f, 0.f, 0.f};
        #pragma unroll
        for (int j = 0; j < 8; ++j) {
            f32x4 t = acc[i][j];
            #pragma unroll
            for (int r = 0; r < 4; ++r) {
                float v = geluf(t[r] + b1c[j]);
                t[r] = v; S[r] += v; S2[r] += v * v;
            }
            acc[i][j] = t;
        }
        #pragma unroll
        for (int r = 0; r < 4; ++r) {
            #pragma unroll
            for (int m = 1; m <= 8; m <<= 1) {
                S[r] += __shfl_xor(S[r], m, 64);
                S2[r] += __shfl_xor(S2[r], m, 64);
            }
            if (lr == 0) {
                int rowl = wr * 32 + i * 16 + 4 * g + r;
                part[rowl][wc][0] = S[r];
                part[rowl][wc][1] = S2[r];
            }
        }
    }
    __syncthreads();
    float c0[2][4], c1[2][4];
    #pragma unroll
    for (int i = 0; i < 2; ++i)
        #pragma unroll
        for (int r = 0; r < 4; ++r) {
            int rowl = wr * 32 + i * 16 + 4 * g + r;
            float S = part[rowl][0][0] + part[rowl][1][0];
            float S2 = part[rowl][0][1] + part[rowl][1][1];
            float mu = S * (1.f / 256.f);
            float var = S2 * (1.f / 256.f) - mu * mu;
            float rs = rsqrtf(var + 1e-5f);
            c1[i][r] = rs; c0[i][r] = -mu * rs;
        }
    __syncthreads();   // part reads done; Bs free since k-loop's last barrier
    // transpose y=(v-mu)*rs (g1,b1 folded into W2'/bias2) into Bs flat [64][256 KP-chunked]
    u16* trans = &Bs[0][0];
    #pragma unroll
    for (int i = 0; i < 2; ++i)
        #pragma unroll
        for (int j = 0; j < 8; ++j) {
            int pos = wc * 128 + (j >> 1) * 32 + (((lr & 12) << 1) | ((j & 1) << 2) | (lr & 3));
            #pragma unroll
            for (int r = 0; r < 4; ++r) {
                int rowl = wr * 32 + i * 16 + 4 * g + r;
                trans[rowl * 256 + pos] = f2bf(fmaf(acc[i][j][r], c1[i][r], c0[i][r]));
            }
        }
    __syncthreads();

    // ======== fused h2: y[64x256] @ W2'[256x128] (+bias2, gelu, LN, dot W3) -> scores ========
    {
        s16x8 af2[8];
        #pragma unroll
        for (int ks = 0; ks < 8; ++ks)
            af2[ks] = *(const s16x8*)&trans[(wv * 16 + lr) * 256 + ks * 32 + g * 8];
        float bc2[8], g2c[8], b2c[8], w3c[8];
        #pragma unroll
        for (int j = 0; j < 8; ++j) {
            int col = j * 16 + lr;
            bc2[j] = bias2[col]; g2c[j] = g2v[col]; b2c[j] = b2v[col]; w3c[j] = W3[col];
        }
        float b3v = b3[0];
        const u16* w2b = w2t + (size_t)lr * 32 + g * 8;   // + ks*4096 + j*512
        s16x8 bA2[8], bB2[8];
        #pragma unroll
        for (int j = 0; j < 8; ++j) bA2[j] = *(const s16x8*)(w2b + (size_t)j * 512);
        f32x4 acc2[8];
        #pragma unroll
        for (int j = 0; j < 8; ++j) acc2[j] = (f32x4){0.f, 0.f, 0.f, 0.f};
        #pragma unroll
        for (int kp = 0; kp < 4; ++kp) {
            const int ks0 = 2 * kp, ks1 = ks0 + 1;
            #pragma unroll
            for (int j = 0; j < 8; ++j)
                bB2[j] = *(const s16x8*)(w2b + (size_t)ks1 * 4096 + j * 512);
            #pragma unroll
            for (int j = 0; j < 8; ++j) acc2[j] = MFMA(af2[ks0], bA2[j], acc2[j]);
            if (kp < 3) {
                #pragma unroll
                for (int j = 0; j < 8; ++j)
                    bA2[j] = *(const s16x8*)(w2b + (size_t)(ks0 + 2) * 4096 + j * 512);
            }
            #pragma unroll
            for (int j = 0; j < 8; ++j) acc2[j] = MFMA(af2[ks1], bB2[j], acc2[j]);
        }
        float T[4] = {0.f, 0.f, 0.f, 0.f}, T2[4] = {0.f, 0.f, 0.f, 0.f};
        #pragma unroll
        for (int j = 0; j < 8; ++j) {
            f32x4 t = acc2[j];
            #pragma unroll
            for (int r = 0; r < 4; ++r) {
                float v = geluf(t[r] + bc2[j]);
                t[r] = v; T[r] += v; T2[r] += v * v;
            }
            acc2[j] = t;
        }
        #pragma unroll
        for (int r = 0; r < 4; ++r) {
            #pragma unroll
            for (int m = 1; m <= 8; m <<= 1) {
                T[r] += __shfl_xor(T[r], m, 64);
                T2[r] += __shfl_xor(T2[r], m, 64);
            }
            float mu = T[r] * (1.f / 128.f);
            float var = T2[r] * (1.f / 128.f) - mu * mu;
            float rs = rsqrtf(var + 1e-5f);
            float dd = 0.f;
            #pragma unroll
            for (int j = 0; j < 8; ++j) {
                float ln = (acc2[j][r] - mu) * rs * g2c[j] + b2c[j];
                dd = fmaf(ln, w3c[j], dd);
            }
            #pragma unroll
            for (int m = 1; m <= 8; m <<= 1) dd += __shfl_xor(dd, m, 64);
            if (lr == 0) scores[blk * 64 + wv * 16 + 4 * g + r] = dd + b3v;
        }
    }
}

// ---------- out[b] = sigmoid( sum_{n,h} score*gate*mask / 8 ), rows' = (b*128+n)*8+h
__global__ __launch_bounds__(256) void final_kernel(
    const float* __restrict__ scores, const float* __restrict__ idfs,
    const float* __restrict__ mask, const float* __restrict__ gate_w,
    const float* __restrict__ gate_b, float* __restrict__ outp)
{
    int b = blockIdx.x, tid = threadIdx.x;
    float gw = gate_w[0], gb = gate_b[0];
    float acc = 0.f;
    for (int i = tid; i < 1024; i += 256) {
        int n = i >> 3;
        float lg = log1pf(idfs[b * 128 + n]);
        float gate = 1.f / (1.f + expf(-(lg * gw + gb)));
        acc += scores[b * 1024 + i] * gate * mask[b * 128 + n];
    }
    acc = wave_reduce_sum(acc);
    __shared__ float wsum[4];
    if ((tid & 63) == 0) wsum[tid >> 6] = acc;
    __syncthreads();
    if (tid == 0) {
        float t = wsum[0] + wsum[1] + wsum[2] + wsum[3];
        outp[b] = 1.f / (1.f + expf(-t * 0.125f));
    }
}

extern "C" void kernel_launch(void* const* d_in, const int* in_sizes, int n_in,
                              void* d_out, int out_size, void* d_ws, size_t ws_size,
                              hipStream_t stream) {
    const float* q_emb    = (const float*)d_in[0];
    const float* ent      = (const float*)d_in[1];
    const int*   roles    = (const int*)d_in[2];
    const float* idfs     = (const float*)d_in[3];
    const float* mask     = (const float*)d_in[4];
    const float* role_emb = (const float*)d_in[5];
    const float* ln_f_g   = (const float*)d_in[6];
    const float* ln_f_b   = (const float*)d_in[7];
    const float* Wq       = (const float*)d_in[8];
    const float* bq       = (const float*)d_in[9];
    const float* Wk       = (const float*)d_in[10];
    const float* bk       = (const float*)d_in[11];
    const float* W1       = (const float*)d_in[12];
    const float* b1       = (const float*)d_in[13];
    const float* ln1_g    = (const float*)d_in[14];
    const float* ln1_b    = (const float*)d_in[15];
    const float* W2       = (const float*)d_in[16];
    const float* b2       = (const float*)d_in[17];
    const float* ln2_g    = (const float*)d_in[18];
    const float* ln2_b    = (const float*)d_in[19];
    const float* W3       = (const float*)d_in[20];
    const float* b3       = (const float*)d_in[21];
    const float* gate_w   = (const float*)d_in[22];
    const float* gate_b   = (const float*)d_in[23];
    float* outp = (float*)d_out;

    // workspace layout (bytes), disjoint; peak ~32 MB
    char* ws = (char*)d_ws;
    u16*   nfb    = (u16*)(ws);                          // 12,582,912
    u16*   kbuf   = (u16*)(ws + (size_t)12582912);       // 16,777,216
    u16*   WkT    = (u16*)(ws + (size_t)29360128);       //  1,572,864
    u16*   W1T    = (u16*)(ws + (size_t)30932992);       //    262,144
    u16*   W2T    = (u16*)(ws + (size_t)31195136);       //     65,536
    u16*   qbuf   = (u16*)(ws + (size_t)31260672);       //    131,072
    float* bias2  = (float*)(ws + (size_t)31391744);     //        512
    float* scores = (float*)(ws + (size_t)31392256);     //    262,144

    prep_all<<<3713, 256, 0, stream>>>(Wk, WkT, W1, W1T, W2, ln1_g, W2T, ln1_b, b2, bias2);
    nf_ln_kernel<<<2048, 256, 0, stream>>>(ent, roles, role_emb, ln_f_g, ln_f_b, nfb);
    q_kernel<<<dim3(4, 64), 256, 0, stream>>>(q_emb, Wq, bq, qbuf);
    kgemm<<<dim3(8, 64), 256, 0, stream>>>(nfb, WkT, bk, kbuf);
    h1<<<1024, 256, 0, stream>>>(kbuf, qbuf, W1T, b1, W2T, bias2,
                                 ln2_g, ln2_b, W3, b3, scores);
    final_kernel<<<64, 256, 0, stream>>>(scores, idfs, mask, gate_w, gate_b, outp);
}